// Round 1
// baseline (1135.912 us; speedup 1.0000x reference)
//
#include <hip/hip_runtime.h>
#include <hip/hip_bf16.h>

#define B_ 128
#define H_ 512
#define S_ 2048
#define ST 64          // s-tile per pass-1 block
#define NP (S_/ST)     // 32 partials per batch
#define RB 520         // LDS row stride (elements) for Bs: 16B-aligned rows

typedef short  bf16x8  __attribute__((ext_vector_type(8)));
typedef float  floatx4 __attribute__((ext_vector_type(4)));

__device__ __forceinline__ unsigned short f2bf(float f){
  unsigned u = __float_as_uint(f);
  unsigned r = (u + 0x7fffu + ((u >> 16) & 1u)) >> 16;   // RNE
  return (unsigned short)r;
}
__device__ __forceinline__ float bf2f(unsigned short h){
  return __uint_as_float(((unsigned)h) << 16);
}
__device__ __forceinline__ float fast_tanh(float x){
  x = fminf(15.f, fmaxf(-15.f, x));
  float e = __expf(2.f * x);
  return (e - 1.f) * __builtin_amdgcn_rcpf(e + 1.f);
}

// ---------------- k0: W_att fp32 -> bf16 ----------------
typedef short short4v __attribute__((ext_vector_type(4)));
__global__ __launch_bounds__(256) void k_convW(const float* __restrict__ W,
                                               unsigned short* __restrict__ Wb){
  int i = (blockIdx.x * 256 + threadIdx.x) * 4;
  float4 v = *(const float4*)(W + i);
  short4v o;
  o[0] = (short)f2bf(v.x); o[1] = (short)f2bf(v.y);
  o[2] = (short)f2bf(v.z); o[3] = (short)f2bf(v.w);
  *(short4v*)(Wb + i) = o;
}

// ---------------- k1: scores GEMM + tanh.v_att + partial softmax/context ----
__global__ __launch_bounds__(256, 2) void k_pass1(
    const float* __restrict__ hidden, const float* __restrict__ v_att,
    const unsigned short* __restrict__ Wb,
    float* __restrict__ part_m, float* __restrict__ part_z,
    float* __restrict__ part_ctx)
{
  __shared__ unsigned short Bs[ST * RB];   // hidden tile, bf16, [s][k] transposed
  __shared__ float vatt[H_];
  __shared__ float twav[4][ST];
  __shared__ float ts[ST];
  __shared__ float es[ST];

  const int tid = threadIdx.x;
  const int w = tid >> 6, l = tid & 63;
  const int p = blockIdx.x & (NP - 1);
  const int b = blockIdx.x >> 5;          // NP == 32
  const int s0 = p * ST;

  vatt[tid]       = v_att[tid];
  vatt[tid + 256] = v_att[tid + 256];

  // Stage hidden[b, :, s0:s0+64] -> bf16 LDS transposed [s][k].
  // Lane gathers 8 consecutive k for its s (each k-row read coalesced across the
  // wave), then one 16B ds_write_b128 (bank-uniform).
  {
    const float* src0 = hidden + ((size_t)b * H_) * S_ + s0 + l;
    #pragma unroll
    for (int it = 0; it < 16; ++it){
      int kb = it * 32 + w * 8;
      const float* src = src0 + (size_t)kb * S_;
      bf16x8 pk;
      #pragma unroll
      for (int j = 0; j < 8; ++j)
        pk[j] = (short)f2bf(src[(size_t)j * S_]);
      *(bf16x8*)(&Bs[l * RB + kb]) = pk;
    }
  }
  __syncthreads();

  const int quad = l >> 4, l16 = l & 15;
  float tacc[4] = {0.f, 0.f, 0.f, 0.f};

  // Each wave: 8 h-tiles (2 outer iters x 4 concurrent), 4 s-subtiles of 16.
  for (int o = 0; o < 2; ++o){
    const int htbase = w * 8 + o * 4;
    floatx4 acc[4][4];
    #pragma unroll
    for (int ti = 0; ti < 4; ++ti)
      #pragma unroll
      for (int ss = 0; ss < 4; ++ss){
        floatx4 z4 = {0.f, 0.f, 0.f, 0.f};
        acc[ti][ss] = z4;
      }

    for (int k0 = 0; k0 < H_; k0 += 32){
      bf16x8 a[4];
      #pragma unroll
      for (int ti = 0; ti < 4; ++ti)
        a[ti] = *(const bf16x8*)(Wb + ((htbase + ti) * 16 + l16) * H_ + k0 + quad * 8);
      bf16x8 bb[4];
      #pragma unroll
      for (int ss = 0; ss < 4; ++ss)
        bb[ss] = *(const bf16x8*)(&Bs[(ss * 16 + l16) * RB + k0 + quad * 8]);
      #pragma unroll
      for (int ti = 0; ti < 4; ++ti)
        #pragma unroll
        for (int ss = 0; ss < 4; ++ss)
          acc[ti][ss] = __builtin_amdgcn_mfma_f32_16x16x32_bf16(a[ti], bb[ss], acc[ti][ss], 0, 0, 0);
    }

    // Epilogue: t[s] += v_att[h] * tanh(score[h][s]).
    // C/D layout: col = lane&15 (s), row = quad*4 + reg (h).
    #pragma unroll
    for (int ti = 0; ti < 4; ++ti){
      const int hbase = (htbase + ti) * 16 + quad * 4;
      #pragma unroll
      for (int r = 0; r < 4; ++r){
        float va = vatt[hbase + r];
        #pragma unroll
        for (int ss = 0; ss < 4; ++ss)
          tacc[ss] += va * fast_tanh(acc[ti][ss][r]);
      }
    }
  }

  #pragma unroll
  for (int ss = 0; ss < 4; ++ss){
    tacc[ss] += __shfl_xor(tacc[ss], 16);
    tacc[ss] += __shfl_xor(tacc[ss], 32);
  }
  if (l < 16){
    #pragma unroll
    for (int ss = 0; ss < 4; ++ss) twav[w][ss * 16 + l] = tacc[ss];
  }
  __syncthreads();
  if (tid < ST) ts[tid] = twav[0][tid] + twav[1][tid] + twav[2][tid] + twav[3][tid];
  __syncthreads();

  float m = -1e30f;
  for (int s = 0; s < ST; ++s) m = fmaxf(m, ts[s]);
  if (tid < ST) es[tid] = __expf(ts[tid] - m);
  __syncthreads();
  float z = 0.f;
  for (int s = 0; s < ST; ++s) z += es[s];

  const int pidx = b * NP + p;
  if (tid == 0){ part_m[pidx] = m; part_z[pidx] = z; }

  // Partial (unnormalized) context from the bf16 LDS copy.
  for (int h = tid; h < H_; h += 256){
    float a = 0.f;
    for (int s = 0; s < ST; ++s) a += es[s] * bf2f(Bs[s * RB + h]);
    part_ctx[(size_t)pidx * H_ + h] = a;
  }
}

// ---------------- k2: combine partials -> context -> 2-layer MLP ------------
__global__ __launch_bounds__(256) void k_mlp(
    const float* __restrict__ part_m, const float* __restrict__ part_z,
    const float* __restrict__ part_ctx,
    const float* __restrict__ fc1_w, const float* __restrict__ fc1_b,
    const float* __restrict__ fc2_w, const float* __restrict__ fc2_b,
    float* __restrict__ out2)
{
  __shared__ float ctx[H_];
  __shared__ float h1[H_];
  __shared__ float wp[NP];
  const int b = blockIdx.x, tid = threadIdx.x;

  float m = -1e30f;
  for (int pp = 0; pp < NP; ++pp) m = fmaxf(m, part_m[b * NP + pp]);
  if (tid < NP) wp[tid] = __expf(part_m[b * NP + tid] - m);
  __syncthreads();
  float z = 0.f;
  for (int pp = 0; pp < NP; ++pp) z += wp[pp] * part_z[b * NP + pp];
  float invz = 1.f / z;

  for (int h = tid; h < H_; h += 256){
    float a = 0.f;
    for (int pp = 0; pp < NP; ++pp) a += wp[pp] * part_ctx[(size_t)(b * NP + pp) * H_ + h];
    ctx[h] = a * invz;
  }
  __syncthreads();

  for (int i = tid; i < H_; i += 256){
    const float4* row = (const float4*)(fc1_w + (size_t)i * H_);
    float4 s4 = {0.f, 0.f, 0.f, 0.f};
    for (int j = 0; j < H_ / 4; ++j){
      float4 wv = row[j];
      s4.x += wv.x * ctx[4 * j];     s4.y += wv.y * ctx[4 * j + 1];
      s4.z += wv.z * ctx[4 * j + 2]; s4.w += wv.w * ctx[4 * j + 3];
    }
    h1[i] = fmaxf(fc1_b[i] + s4.x + s4.y + s4.z + s4.w, 0.f);
  }
  __syncthreads();

  for (int i = tid; i < H_; i += 256){
    const float4* row = (const float4*)(fc2_w + (size_t)i * H_);
    float4 s4 = {0.f, 0.f, 0.f, 0.f};
    for (int j = 0; j < H_ / 4; ++j){
      float4 wv = row[j];
      s4.x += wv.x * h1[4 * j];     s4.y += wv.y * h1[4 * j + 1];
      s4.z += wv.z * h1[4 * j + 2]; s4.w += wv.w * h1[4 * j + 3];
    }
    out2[(size_t)b * H_ + i] = fmaxf(fc2_b[i] + s4.x + s4.y + s4.z + s4.w, 0.f);
  }
}

// ---------------- k3: probs[b,s] = sum_h v_ptr[h]*tanh(hidden+out) ----------
__global__ __launch_bounds__(256) void k_probs(
    const float* __restrict__ hidden, const float* __restrict__ v_ptr,
    const float* __restrict__ out2, float* __restrict__ probs)
{
  __shared__ float vp[H_], ob[H_];
  const int b = blockIdx.y, c = blockIdx.x, tid = threadIdx.x;
  vp[tid]       = v_ptr[tid];
  vp[tid + 256] = v_ptr[tid + 256];
  ob[tid]       = out2[(size_t)b * H_ + tid];
  ob[tid + 256] = out2[(size_t)b * H_ + tid + 256];
  __syncthreads();

  const int s = c * 512 + tid * 2;
  const float* base = hidden + (size_t)b * H_ * S_ + s;
  float a0 = 0.f, a1 = 0.f;
  #pragma unroll 4
  for (int h = 0; h < H_; ++h){
    float2 hv = *(const float2*)(base + (size_t)h * S_);
    float wv = vp[h], o = ob[h];
    a0 += wv * fast_tanh(hv.x + o);
    a1 += wv * fast_tanh(hv.y + o);
  }
  probs[(size_t)b * S_ + s]     = a0;
  probs[(size_t)b * S_ + s + 1] = a1;
}

// ---------------- launcher ----------------
extern "C" void kernel_launch(void* const* d_in, const int* in_sizes, int n_in,
                              void* d_out, int out_size, void* d_ws, size_t ws_size,
                              hipStream_t stream)
{
  const float* hidden = (const float*)d_in[0];
  const float* v_att  = (const float*)d_in[1];
  const float* W_att  = (const float*)d_in[2];
  const float* v_ptr  = (const float*)d_in[3];
  const float* fc1_w  = (const float*)d_in[4];
  const float* fc1_b  = (const float*)d_in[5];
  const float* fc2_w  = (const float*)d_in[6];
  const float* fc2_b  = (const float*)d_in[7];
  float* probs = (float*)d_out;

  char* ws = (char*)d_ws;
  unsigned short* Wb = (unsigned short*)ws;                        // 512 KiB
  float* part_m   = (float*)(ws + 524288);                         // 16 KiB
  float* part_z   = (float*)(ws + 524288 + 16384);                 // 16 KiB
  float* part_ctx = (float*)(ws + 524288 + 32768);                 // 8 MiB
  float* out2     = (float*)(ws + 524288 + 32768 + 8388608);       // 256 KiB

  hipLaunchKernelGGL(k_convW, dim3(256), dim3(256), 0, stream, W_att, Wb);
  hipLaunchKernelGGL(k_pass1, dim3(B_ * NP), dim3(256), 0, stream,
                     hidden, v_att, Wb, part_m, part_z, part_ctx);
  hipLaunchKernelGGL(k_mlp, dim3(B_), dim3(256), 0, stream,
                     part_m, part_z, part_ctx, fc1_w, fc1_b, fc2_w, fc2_b, out2);
  hipLaunchKernelGGL(k_probs, dim3(4, B_), dim3(256), 0, stream,
                     hidden, v_ptr, out2, probs);
}